// Round 21
// baseline (772.390 us; speedup 1.0000x reference)
//
#include <hip/hip_runtime.h>
#include <hip/hip_bf16.h>

typedef __attribute__((ext_vector_type(4))) int i32x4;
typedef __attribute__((ext_vector_type(8))) int i32x8;
typedef __attribute__((ext_vector_type(4))) float f32x4;

// exact floor(log2(x)) for x > 0 (handles subnormals)
__device__ __forceinline__ int flog2(float x) {
  unsigned u = __float_as_uint(x);
  int e = (int)((u >> 23) & 255u);
  if (e) return e - 127;
  unsigned m = u & 0x7fffffu;
  return (31 - __clz(m)) - 149;
}

// exact 2^e for e in [-252, 254]
__device__ __forceinline__ float exp2i(int e) {
  int e1 = e >> 1, e2 = e - e1;
  return __uint_as_float((unsigned)(e1 + 127) << 23) *
         __uint_as_float((unsigned)(e2 + 127) << 23);
}

// quantize y (already divided by shared scale) to e2m<MFRAC>, round-half-even, saturate
template <int MFRAC>
__device__ __forceinline__ float qelem(float y, float maxn) {
  float ay = fabsf(y);
  int e = (ay == 0.f) ? 0 : flog2(ay);
  if (e < 0) e = 0;  // min_exp = 0 for ebits=2
  float r = rintf(y * exp2i(MFRAC - e)) * exp2i(e - MFRAC);
  return fminf(fmaxf(r, -maxn), maxn);
}

// general RNE fp32 -> OCP e4m3 encode (|v| <= 448; exact on our folded value grid)
__device__ __forceinline__ unsigned char enc_rne(float v) {
  unsigned u = __float_as_uint(v);
  unsigned s = u >> 31;
  float a = fabsf(v);
  if (a == 0.f) return (unsigned char)(s << 7);
  int e = flog2(a);
  if (e < -6) e = -6;                      // subnormal regime
  int qi = (int)rintf(a * exp2i(3 - e));   // RNE to 3-frac-bit grid -> [0,16]
  if (qi == 0) return (unsigned char)(s << 7);
  if (qi == 16) { qi = 8; e += 1; }
  unsigned exf, m;
  if (qi < 8) { exf = 0u; m = (unsigned)qi; }          // e == -6 subnormal
  else { exf = (unsigned)(e + 7); m = (unsigned)(qi - 8); }
  return (unsigned char)((s << 7) | (exf << 3) | m);
}

// fragment-page swizzle: byte address of element (row, col-in-K) in a tensor stored
// as 2KB pages per (16-row-block x 128-K-block); pa = K/128 pages per row-block.
__device__ __forceinline__ size_t swz(int row, int col, int pa) {
  return ((size_t)((row >> 4) * pa + (col >> 7))) * 2048
       + (size_t)(((col >> 4) & 1) * 1024
       + ((row & 15) + ((col >> 5) & 3) * 16) * 16
       + (col & 15));
}

// ------ MX quantization with exponent folding -> fragment-page-swizzled e4m3 bytes ---
template <int MFRAC, int EMAX>
__global__ void quant_fold(const float* __restrict__ in, unsigned char* __restrict__ out,
                           long n4, float maxn, int se0, int kshift, int kmask, int pa) {
  long i = (long)blockIdx.x * blockDim.x + threadIdx.x;
  long stride = (long)gridDim.x * blockDim.x;
  for (; i < n4; i += stride) {
    float4 v = reinterpret_cast<const float4*>(in)[i];
    float am = fmaxf(fmaxf(fabsf(v.x), fabsf(v.y)), fmaxf(fabsf(v.z), fabsf(v.w)));
    am = fmaxf(am, __shfl_xor(am, 1));
    am = fmaxf(am, __shfl_xor(am, 2));
    am = fmaxf(am, __shfl_xor(am, 4));
    int se = ((am == 0.f) ? 0 : flog2(am)) - EMAX;
    se = se < -127 ? -127 : (se > 127 ? 127 : se);
    float inv = exp2i(-se), f = exp2i(se - se0);
    unsigned o = (unsigned)enc_rne(qelem<MFRAC>(v.x * inv, maxn) * f)
               | ((unsigned)enc_rne(qelem<MFRAC>(v.y * inv, maxn) * f) << 8)
               | ((unsigned)enc_rne(qelem<MFRAC>(v.z * inv, maxn) * f) << 16)
               | ((unsigned)enc_rne(qelem<MFRAC>(v.w * inv, maxn) * f) << 24);
    int row = (int)(i >> kshift);
    int kq = ((int)i & kmask) * 4;           // kq % 16 in {0,4,8,12}: 4B stays in-piece
    reinterpret_cast<unsigned*>(out)[swz(row, kq, pa) >> 2] = o;
  }
}

// load one MFMA fragment (lane's 32B) directly from a global fragment page
__device__ __forceinline__ i32x8 gfrag(const unsigned char* page, int l16) {
  i32x4 lo = *reinterpret_cast<const i32x4*>(page + l16);
  i32x4 hi = *reinterpret_cast<const i32x4*>(page + 1024 + l16);
  i32x8 r;
  r[0] = lo[0]; r[1] = lo[1]; r[2] = lo[2]; r[3] = lo[3];
  r[4] = hi[0]; r[5] = hi[1]; r[6] = hi[2]; r[7] = hi[3];
  return r;
}

// ----- fp8 GEMM, 16x16x128 MFMA, NO LDS / NO BARRIERS, DOUBLE-WIDE wave 128x128 ----
// Block 256x256, 4 waves (2x2 of 128x128). Per K-step/wave: 16 frags (8 A + 8 B)
// feed 64 MFMAs (2x R17's 32; probe R20 showed extra MFMAs ride free in the
// per-step overhead window). 1 wave/SIMD (acc 256 + ~170 VGPR); probe 2 showed
// TLP wasn't hiding latency anyway.
// All HW scale bytes = 1.0 (0x7f7f7f7f): convention-immune, full MX instruction rate.
// EPI=0: fp32 out (+ ks split via Cf/Cf2); EPI=1: up-fused (fp32 gate in, fp8 out).
template <int EPI>
__global__ __launch_bounds__(256, 1) void mx_gemm(
    const unsigned char* __restrict__ A, int pa,
    const unsigned char* __restrict__ B, int pb,
    float* __restrict__ Cf, float* __restrict__ Cf2,
    const float* __restrict__ gate, unsigned char* __restrict__ C8,
    int W, int K, int ldC, int c0, float fac, int se0out, int nbx, int nby) {
  const int t = threadIdx.x, l = t & 63, w = t >> 6;
  const int wr = w >> 1, wc = w & 1;          // 2x2 wave grid; wave tile 128x128
  const int lr16 = l & 15, lg16 = l >> 4;
  const int l16 = l * 16;
  const int n = (int)blockIdx.x;
  const int bx = n % nbx, byks = n / nbx;
  const int by = byks % nby, ks = byks / nby;
  const int rowA = bx * 256, rowB = by * 256;
  const int kbs = ks * (K >> 7);               // page offset for K-split
  const int SCL = 0x7f7f7f7f;  // e8m0 1.0 in every byte: scale path is a no-op

  f32x4 acc[8][8];
#pragma unroll
  for (int i = 0; i < 8; ++i)
#pragma unroll
    for (int j = 0; j < 8; ++j) acc[i][j] = (f32x4)(0.f);

  const unsigned char* pApg[8];
  const unsigned char* pBpg[8];
#pragma unroll
  for (int m = 0; m < 8; ++m)
    pApg[m] = A + ((size_t)((rowA >> 4) + wr * 8 + m) * pa + kbs) * 2048;
#pragma unroll
  for (int nn = 0; nn < 8; ++nn)
    pBpg[nn] = B + ((size_t)((rowB >> 4) + wc * 8 + nn) * pb + kbs) * 2048;

  const int nt = K >> 7;  // 16 (gate/up) or 32 (down halves)
  for (int kb = 0; kb < nt; ++kb) {
    i32x8 af[8], bf[8];
#pragma unroll
    for (int m = 0; m < 8; ++m) { af[m] = gfrag(pApg[m], l16); pApg[m] += 2048; }
#pragma unroll
    for (int nn = 0; nn < 8; ++nn) { bf[nn] = gfrag(pBpg[nn], l16); pBpg[nn] += 2048; }
#pragma unroll
    for (int m = 0; m < 8; ++m)
#pragma unroll
      for (int nn = 0; nn < 8; ++nn)
        acc[m][nn] = __builtin_amdgcn_mfma_scale_f32_16x16x128_f8f6f4(
            af[m], bf[nn], acc[m][nn], 0, 0, 0, SCL, 0, SCL);
  }

  // 16x16 C/D layout: col = lane&15, row = (lane>>4)*4 + reg  (m89-verified)
  if (EPI == 0) {
    float* D = ks ? Cf2 : Cf;
#pragma unroll
    for (int m = 0; m < 8; ++m)
#pragma unroll
      for (int nn = 0; nn < 8; ++nn)
#pragma unroll
        for (int r = 0; r < 4; ++r) {
          int row = rowA + wr * 128 + m * 16 + lg16 * 4 + r;
          int col = rowB + wc * 128 + nn * 16 + lr16;
          D[(size_t)row * ldC + c0 + col] = acc[m][nn][r] * fac;
        }
  } else {
    const int pao = ldC >> 7;  // output pages per row-block
#pragma unroll
    for (int m = 0; m < 8; ++m)
#pragma unroll
      for (int p = 0; p < 4; ++p)
#pragma unroll
        for (int r = 0; r < 4; ++r) {
          int row = rowA + wr * 128 + m * 16 + lg16 * 4 + r;
          int col = rowB + wc * 128 + p * 32 + lr16;  // chunk-local column in [0, W)
          float u0 = acc[m][2 * p][r] * fac;
          float u1 = acc[m][2 * p + 1][r] * fac;
          float g0 = gate[(size_t)row * W + col];
          float g1 = gate[(size_t)row * W + col + 16];
          float v0 = u0 * (g0 / (1.f + expf(-g0)));
          float v1 = u1 * (g1 / (1.f + expf(-g1)));
          float am = fmaxf(fabsf(v0), fabsf(v1));
          am = fmaxf(am, __shfl_xor(am, 1));
          am = fmaxf(am, __shfl_xor(am, 2));
          am = fmaxf(am, __shfl_xor(am, 4));
          am = fmaxf(am, __shfl_xor(am, 8));
          int se = ((am == 0.f) ? 0 : flog2(am)) - 2;
          se = se < -127 ? -127 : (se > 127 ? 127 : se);
          float f = exp2i(-se), fo = exp2i(se - se0out);
          C8[swz(row, c0 + col, pao)] = enc_rne(qelem<3>(v0 * f, 7.5f) * fo);
          C8[swz(row, c0 + col + 16, pao)] = enc_rne(qelem<3>(v1 * f, 7.5f) * fo);
        }
  }
}

__global__ void add_f32(float* __restrict__ out, const float* __restrict__ part, long n4) {
  long i = (long)blockIdx.x * blockDim.x + threadIdx.x;
  long stride = (long)gridDim.x * blockDim.x;
  for (; i < n4; i += stride) {
    float4 a = reinterpret_cast<float4*>(out)[i];
    float4 b = reinterpret_cast<const float4*>(part)[i];
    a.x += b.x; a.y += b.y; a.z += b.z; a.w += b.w;
    reinterpret_cast<float4*>(out)[i] = a;
  }
}

extern "C" void kernel_launch(void* const* d_in, const int* in_sizes, int n_in,
                              void* d_out, int out_size, void* d_ws, size_t ws_size,
                              hipStream_t stream) {
  const float* x = (const float*)d_in[0];
  const float* wg = (const float*)d_in[1];
  const float* wu = (const float*)d_in[2];
  const float* wd = (const float*)d_in[3];
  float* out = (float*)d_out;

  const int S = 4096, H = 2048, I = 8192;

  // per-tensor fold baselines: exact while block se in [se0-6, se0+5]
  const int SE0X = -1, SE0W = -7, SE0I = -2;
  const float FAC_GU = 0.00390625f;     // 2^(SE0X + SE0W) = 2^-8
  const float FAC_DN = 0.001953125f;    // 2^(SE0I + SE0W) = 2^-9

  unsigned char* p = (unsigned char*)d_ws;
  unsigned char* xq8 = p;  p += (size_t)S * H;   //  8.4 MB (swizzled pages)
  unsigned char* wgq8 = p; p += (size_t)I * H;   // 16.8 MB
  unsigned char* wuq8 = p; p += (size_t)I * H;   // 16.8 MB
  unsigned char* wdq8 = p; p += (size_t)H * I;   // 16.8 MB
  unsigned char* iq8 = p;  p += (size_t)S * I;   // 33.6 MB
  size_t base_bytes = (size_t)(p - (unsigned char*)d_ws);  // ~92 MB
  float* gatef = (float*)p;          // chunked fp32 gate buffer (exact; feeds requant)
  float* pf = (float*)p;             // down K-split partial (reuses dead gatef)

  // quantize -> fragment-page-swizzled e4m3
  quant_fold<3, 2><<<2048, 256, 0, stream>>>(x, xq8, (long)S * H / 4, 7.5f, SE0X,
                                             9, 511, H / 128);    // K=2048
  quant_fold<1, 2><<<2048, 256, 0, stream>>>(wg, wgq8, (long)I * H / 4, 6.0f, SE0W,
                                             9, 511, H / 128);
  quant_fold<1, 2><<<2048, 256, 0, stream>>>(wu, wuq8, (long)I * H / 4, 6.0f, SE0W,
                                             9, 511, H / 128);
  quant_fold<1, 2><<<2048, 256, 0, stream>>>(wd, wdq8, (long)H * I / 4, 6.0f, SE0W,
                                             11, 2047, I / 128);  // K=8192

  // largest power-of-two column chunk W (multiple of 256) with S*W*4 fp32 gate fitting
  size_t avail = ws_size > base_bytes ? ws_size - base_bytes : 0;
  int W = 256;
  for (int cand = I; cand >= 256; cand >>= 1)
    if ((size_t)S * cand * 4 <= avail) { W = cand; break; }

  for (int c0 = 0; c0 < I; c0 += W) {
    int nbx = S / 256, nby = W / 256;
    // gate chunk -> fp32 gatef [S][W]
    mx_gemm<0><<<nbx * nby, 256, 0, stream>>>(
        xq8, H / 128, wgq8 + (size_t)c0 * H, H / 128, gatef, nullptr,
        nullptr, nullptr, W, H, W, 0, FAC_GU, 0, nbx, nby);
    // up chunk + SwiGLU + fp6-MX requant (folded) -> iq8 pages, columns [c0, c0+W)
    mx_gemm<1><<<nbx * nby, 256, 0, stream>>>(
        xq8, H / 128, wuq8 + (size_t)c0 * H, H / 128, nullptr, nullptr,
        gatef, iq8, W, H, I, c0, FAC_GU, SE0I, nbx, nby);
  }

  // down GEMM, K split in 2 (K = I/2 per half; grid 16*8*2 = 256)
  mx_gemm<0><<<(S / 256) * (H / 256) * 2, 256, 0, stream>>>(
      iq8, I / 128, wdq8, I / 128, out, pf, nullptr, nullptr,
      H, I / 2, H, 0, FAC_DN, 0, S / 256, H / 256);
  add_f32<<<2048, 256, 0, stream>>>(out, pf, (long)S * H / 4);
}

// Round 22
// 415.246 us; speedup vs baseline: 1.8601x; 1.8601x over previous
//
#include <hip/hip_runtime.h>
#include <hip/hip_bf16.h>

typedef __attribute__((ext_vector_type(4))) int i32x4;
typedef __attribute__((ext_vector_type(8))) int i32x8;
typedef __attribute__((ext_vector_type(4))) float f32x4;

// exact floor(log2(x)) for x > 0 (handles subnormals)
__device__ __forceinline__ int flog2(float x) {
  unsigned u = __float_as_uint(x);
  int e = (int)((u >> 23) & 255u);
  if (e) return e - 127;
  unsigned m = u & 0x7fffffu;
  return (31 - __clz(m)) - 149;
}

// exact 2^e for e in [-252, 254]
__device__ __forceinline__ float exp2i(int e) {
  int e1 = e >> 1, e2 = e - e1;
  return __uint_as_float((unsigned)(e1 + 127) << 23) *
         __uint_as_float((unsigned)(e2 + 127) << 23);
}

// quantize y (already divided by shared scale) to e2m<MFRAC>, round-half-even, saturate
template <int MFRAC>
__device__ __forceinline__ float qelem(float y, float maxn) {
  float ay = fabsf(y);
  int e = (ay == 0.f) ? 0 : flog2(ay);
  if (e < 0) e = 0;  // min_exp = 0 for ebits=2
  float r = rintf(y * exp2i(MFRAC - e)) * exp2i(e - MFRAC);
  return fminf(fmaxf(r, -maxn), maxn);
}

// general RNE fp32 -> OCP e4m3 encode (|v| <= 448; exact on our folded value grid)
__device__ __forceinline__ unsigned char enc_rne(float v) {
  unsigned u = __float_as_uint(v);
  unsigned s = u >> 31;
  float a = fabsf(v);
  if (a == 0.f) return (unsigned char)(s << 7);
  int e = flog2(a);
  if (e < -6) e = -6;                      // subnormal regime
  int qi = (int)rintf(a * exp2i(3 - e));   // RNE to 3-frac-bit grid -> [0,16]
  if (qi == 0) return (unsigned char)(s << 7);
  if (qi == 16) { qi = 8; e += 1; }
  unsigned exf, m;
  if (qi < 8) { exf = 0u; m = (unsigned)qi; }          // e == -6 subnormal
  else { exf = (unsigned)(e + 7); m = (unsigned)(qi - 8); }
  return (unsigned char)((s << 7) | (exf << 3) | m);
}

// fragment-page swizzle: byte address of element (row, col-in-K) in a tensor stored
// as 2KB pages per (16-row-block x 128-K-block); pa = K/128 pages per row-block.
__device__ __forceinline__ size_t swz(int row, int col, int pa) {
  return ((size_t)((row >> 4) * pa + (col >> 7))) * 2048
       + (size_t)(((col >> 4) & 1) * 1024
       + ((row & 15) + ((col >> 5) & 3) * 16) * 16
       + (col & 15));
}

// ------ MX quantization with exponent folding -> fragment-page-swizzled e4m3 bytes ---
template <int MFRAC, int EMAX>
__global__ void quant_fold(const float* __restrict__ in, unsigned char* __restrict__ out,
                           long n4, float maxn, int se0, int kshift, int kmask, int pa) {
  long i = (long)blockIdx.x * blockDim.x + threadIdx.x;
  long stride = (long)gridDim.x * blockDim.x;
  for (; i < n4; i += stride) {
    float4 v = reinterpret_cast<const float4*>(in)[i];
    float am = fmaxf(fmaxf(fabsf(v.x), fabsf(v.y)), fmaxf(fabsf(v.z), fabsf(v.w)));
    am = fmaxf(am, __shfl_xor(am, 1));
    am = fmaxf(am, __shfl_xor(am, 2));
    am = fmaxf(am, __shfl_xor(am, 4));
    int se = ((am == 0.f) ? 0 : flog2(am)) - EMAX;
    se = se < -127 ? -127 : (se > 127 ? 127 : se);
    float inv = exp2i(-se), f = exp2i(se - se0);
    unsigned o = (unsigned)enc_rne(qelem<MFRAC>(v.x * inv, maxn) * f)
               | ((unsigned)enc_rne(qelem<MFRAC>(v.y * inv, maxn) * f) << 8)
               | ((unsigned)enc_rne(qelem<MFRAC>(v.z * inv, maxn) * f) << 16)
               | ((unsigned)enc_rne(qelem<MFRAC>(v.w * inv, maxn) * f) << 24);
    int row = (int)(i >> kshift);
    int kq = ((int)i & kmask) * 4;           // kq % 16 in {0,4,8,12}: 4B stays in-piece
    reinterpret_cast<unsigned*>(out)[swz(row, kq, pa) >> 2] = o;
  }
}

// load one MFMA fragment (lane's 32B) directly from a global fragment page
__device__ __forceinline__ i32x8 gfrag(const unsigned char* page, int l16) {
  i32x4 lo = *reinterpret_cast<const i32x4*>(page + l16);
  i32x4 hi = *reinterpret_cast<const i32x4*>(page + 1024 + l16);
  i32x8 r;
  r[0] = lo[0]; r[1] = lo[1]; r[2] = lo[2]; r[3] = lo[3];
  r[4] = hi[0]; r[5] = hi[1]; r[6] = hi[2]; r[7] = hi[3];
  return r;
}

// ----- FUSED gate+up GEMM, 16x16x128 MFMA, NO LDS / NO BARRIERS -------------------
// Block 128x128 (S x I), 4 waves (2x2 of 64x64 output, DUAL accumulators).
// Per K-step: 12 gfrag (4 A shared + 4 Bg + 4 Bu) feed 32 MFMAs (16 gate + 16 up).
// Same register footprint as R17 (acc 128, operands 96). Gate never touches memory:
// silu(g)*u + fp6-MX requant in-register -> iq8 pages.
__global__ __launch_bounds__(256, 2) void mx_gateup(
    const unsigned char* __restrict__ A, int pa,
    const unsigned char* __restrict__ Bg, const unsigned char* __restrict__ Bu, int pb,
    unsigned char* __restrict__ C8, int ldC, float fac, int se0out, int nby) {
  const int t = threadIdx.x, l = t & 63, w = t >> 6;
  const int wr = w >> 1, wc = w & 1;          // 2x2 wave grid; wave output 64x64
  const int lr16 = l & 15, lg16 = l >> 4;
  const int l16 = l * 16;
  const int n = (int)blockIdx.x;
  const int bx = n % 32, by = n / 32;          // 32 x nby grid
  const int rowA = bx * 128, rowB = by * 128;
  const int SCL = 0x7f7f7f7f;  // e8m0 1.0 in every byte: scale path is a no-op

  f32x4 accg[4][4], accu[4][4];
#pragma unroll
  for (int i = 0; i < 4; ++i)
#pragma unroll
    for (int j = 0; j < 4; ++j) { accg[i][j] = (f32x4)(0.f); accu[i][j] = (f32x4)(0.f); }

  const unsigned char* pApg[4];
  const unsigned char* pBg[4];
  const unsigned char* pBu[4];
#pragma unroll
  for (int m = 0; m < 4; ++m) {
    pApg[m] = A + (size_t)((rowA >> 4) + wr * 4 + m) * pa * 2048;
    pBg[m] = Bg + (size_t)((rowB >> 4) + wc * 4 + m) * pb * 2048;
    pBu[m] = Bu + (size_t)((rowB >> 4) + wc * 4 + m) * pb * 2048;
  }

  const int nt = pa;  // K = 2048 -> 16 pages (pa == K/128 for A and B alike)
#pragma unroll 2
  for (int kb = 0; kb < nt; ++kb) {
    i32x8 af[4], bg[4], bu[4];
#pragma unroll
    for (int m = 0; m < 4; ++m) { af[m] = gfrag(pApg[m], l16); pApg[m] += 2048; }
#pragma unroll
    for (int m = 0; m < 4; ++m) { bg[m] = gfrag(pBg[m], l16); pBg[m] += 2048; }
#pragma unroll
    for (int m = 0; m < 4; ++m) { bu[m] = gfrag(pBu[m], l16); pBu[m] += 2048; }
#pragma unroll
    for (int m = 0; m < 4; ++m)
#pragma unroll
      for (int nn = 0; nn < 4; ++nn) {
        accg[m][nn] = __builtin_amdgcn_mfma_scale_f32_16x16x128_f8f6f4(
            af[m], bg[nn], accg[m][nn], 0, 0, 0, SCL, 0, SCL);
        accu[m][nn] = __builtin_amdgcn_mfma_scale_f32_16x16x128_f8f6f4(
            af[m], bu[nn], accu[m][nn], 0, 0, 0, SCL, 0, SCL);
      }
  }

  // epilogue: v = silu(g)*u, fp6-MX requant along 32-col blocks, fp8 out (pages)
  // 16x16 C/D layout: col = lane&15, row = (lane>>4)*4 + reg  (m89-verified)
  const int pao = ldC >> 7;
#pragma unroll
  for (int m = 0; m < 4; ++m)
#pragma unroll
    for (int p = 0; p < 2; ++p)
#pragma unroll
      for (int r = 0; r < 4; ++r) {
        int row = rowA + wr * 64 + m * 16 + lg16 * 4 + r;
        int col = rowB + wc * 64 + p * 32 + lr16;
        float g0 = accg[m][2 * p][r] * fac;
        float g1 = accg[m][2 * p + 1][r] * fac;
        float u0 = accu[m][2 * p][r] * fac;
        float u1 = accu[m][2 * p + 1][r] * fac;
        float v0 = u0 * (g0 / (1.f + expf(-g0)));
        float v1 = u1 * (g1 / (1.f + expf(-g1)));
        float am = fmaxf(fabsf(v0), fabsf(v1));
        am = fmaxf(am, __shfl_xor(am, 1));
        am = fmaxf(am, __shfl_xor(am, 2));
        am = fmaxf(am, __shfl_xor(am, 4));
        am = fmaxf(am, __shfl_xor(am, 8));
        int se = ((am == 0.f) ? 0 : flog2(am)) - 2;
        se = se < -127 ? -127 : (se > 127 ? 127 : se);
        float f = exp2i(-se), fo = exp2i(se - se0out);
        C8[swz(row, col, pao)] = enc_rne(qelem<3>(v0 * f, 7.5f) * fo);
        C8[swz(row, col + 16, pao)] = enc_rne(qelem<3>(v1 * f, 7.5f) * fo);
      }
}

// ----- down GEMM (R17 structure): wave tile 64x128, fp32 out, K-split via Cf/Cf2 ----
__global__ __launch_bounds__(256, 2) void mx_down(
    const unsigned char* __restrict__ A, int pa,
    const unsigned char* __restrict__ B, int pb,
    float* __restrict__ Cf, float* __restrict__ Cf2,
    int K, int ldC, float fac, int nby) {
  const int t = threadIdx.x, l = t & 63, w = t >> 6;
  const int wr = w >> 1, wc = w & 1;          // 2x2 wave grid; wave tile 64x128
  const int lr16 = l & 15, lg16 = l >> 4;
  const int l16 = l * 16;
  const int n = (int)blockIdx.x;
  const int bx = n & 31, byks = n >> 5;
  const int by = byks % nby, ks = byks / nby;
  const int rowA = bx * 128, rowB = by * 256;
  const int kbs = ks * (K >> 7);
  const int SCL = 0x7f7f7f7f;

  f32x4 acc[4][8];
#pragma unroll
  for (int i = 0; i < 4; ++i)
#pragma unroll
    for (int j = 0; j < 8; ++j) acc[i][j] = (f32x4)(0.f);

  const unsigned char* pApg[4];
  const unsigned char* pBpg[8];
#pragma unroll
  for (int m = 0; m < 4; ++m)
    pApg[m] = A + ((size_t)((rowA >> 4) + wr * 4 + m) * pa + kbs) * 2048;
#pragma unroll
  for (int nn = 0; nn < 8; ++nn)
    pBpg[nn] = B + ((size_t)((rowB >> 4) + wc * 8 + nn) * pb + kbs) * 2048;

  const int nt = K >> 7;
#pragma unroll 2
  for (int kb = 0; kb < nt; ++kb) {
    i32x8 af[4], bf[8];
#pragma unroll
    for (int m = 0; m < 4; ++m) { af[m] = gfrag(pApg[m], l16); pApg[m] += 2048; }
#pragma unroll
    for (int nn = 0; nn < 8; ++nn) { bf[nn] = gfrag(pBpg[nn], l16); pBpg[nn] += 2048; }
#pragma unroll
    for (int m = 0; m < 4; ++m)
#pragma unroll
      for (int nn = 0; nn < 8; ++nn)
        acc[m][nn] = __builtin_amdgcn_mfma_scale_f32_16x16x128_f8f6f4(
            af[m], bf[nn], acc[m][nn], 0, 0, 0, SCL, 0, SCL);
  }

  float* D = ks ? Cf2 : Cf;
#pragma unroll
  for (int m = 0; m < 4; ++m)
#pragma unroll
    for (int nn = 0; nn < 8; ++nn)
#pragma unroll
      for (int r = 0; r < 4; ++r) {
        int row = rowA + wr * 64 + m * 16 + lg16 * 4 + r;
        int col = rowB + wc * 128 + nn * 16 + lr16;
        D[(size_t)row * ldC + col] = acc[m][nn][r] * fac;
      }
}

__global__ void add_f32(float* __restrict__ out, const float* __restrict__ part, long n4) {
  long i = (long)blockIdx.x * blockDim.x + threadIdx.x;
  long stride = (long)gridDim.x * blockDim.x;
  for (; i < n4; i += stride) {
    float4 a = reinterpret_cast<float4*>(out)[i];
    float4 b = reinterpret_cast<const float4*>(part)[i];
    a.x += b.x; a.y += b.y; a.z += b.z; a.w += b.w;
    reinterpret_cast<float4*>(out)[i] = a;
  }
}

extern "C" void kernel_launch(void* const* d_in, const int* in_sizes, int n_in,
                              void* d_out, int out_size, void* d_ws, size_t ws_size,
                              hipStream_t stream) {
  const float* x = (const float*)d_in[0];
  const float* wg = (const float*)d_in[1];
  const float* wu = (const float*)d_in[2];
  const float* wd = (const float*)d_in[3];
  float* out = (float*)d_out;

  const int S = 4096, H = 2048, I = 8192;

  // per-tensor fold baselines: exact while block se in [se0-6, se0+5]
  const int SE0X = -1, SE0W = -7, SE0I = -2;
  const float FAC_GU = 0.00390625f;     // 2^(SE0X + SE0W) = 2^-8
  const float FAC_DN = 0.001953125f;    // 2^(SE0I + SE0W) = 2^-9

  unsigned char* p = (unsigned char*)d_ws;
  unsigned char* xq8 = p;  p += (size_t)S * H;   //  8.4 MB (swizzled pages)
  unsigned char* wgq8 = p; p += (size_t)I * H;   // 16.8 MB
  unsigned char* wuq8 = p; p += (size_t)I * H;   // 16.8 MB
  unsigned char* wdq8 = p; p += (size_t)H * I;   // 16.8 MB
  unsigned char* iq8 = p;  p += (size_t)S * I;   // 33.6 MB
  float* pf = (float*)p;                         // down K-split partial, 33.6 MB

  // quantize -> fragment-page-swizzled e4m3
  quant_fold<3, 2><<<2048, 256, 0, stream>>>(x, xq8, (long)S * H / 4, 7.5f, SE0X,
                                             9, 511, H / 128);    // K=2048
  quant_fold<1, 2><<<2048, 256, 0, stream>>>(wg, wgq8, (long)I * H / 4, 6.0f, SE0W,
                                             9, 511, H / 128);
  quant_fold<1, 2><<<2048, 256, 0, stream>>>(wu, wuq8, (long)I * H / 4, 6.0f, SE0W,
                                             9, 511, H / 128);
  quant_fold<1, 2><<<2048, 256, 0, stream>>>(wd, wdq8, (long)H * I / 4, 6.0f, SE0W,
                                             11, 2047, I / 128);  // K=8192

  // fused gate+up + SwiGLU + fp6-MX requant -> iq8 pages (grid 32 x 64 = 2048)
  mx_gateup<<<32 * (I / 128), 256, 0, stream>>>(
      xq8, H / 128, wgq8, wuq8, H / 128, iq8, I, FAC_GU, SE0I, I / 128);

  // down GEMM, K split in 2 (K = I/2 per half; grid 32*8*2 = 512)
  mx_down<<<32 * (H / 256) * 2, 256, 0, stream>>>(
      iq8, I / 128, wdq8, I / 128, out, pf, I / 2, H, FAC_DN, H / 256);
  add_f32<<<2048, 256, 0, stream>>>(out, pf, (long)S * H / 4);
}

// Round 23
// 415.178 us; speedup vs baseline: 1.8604x; 1.0002x over previous
//
#include <hip/hip_runtime.h>
#include <hip/hip_bf16.h>

typedef __attribute__((ext_vector_type(4))) int i32x4;
typedef __attribute__((ext_vector_type(8))) int i32x8;
typedef __attribute__((ext_vector_type(4))) float f32x4;

// exact floor(log2(x)) for x > 0 (handles subnormals)
__device__ __forceinline__ int flog2(float x) {
  unsigned u = __float_as_uint(x);
  int e = (int)((u >> 23) & 255u);
  if (e) return e - 127;
  unsigned m = u & 0x7fffffu;
  return (31 - __clz(m)) - 149;
}

// exact 2^e for e in [-252, 254]
__device__ __forceinline__ float exp2i(int e) {
  int e1 = e >> 1, e2 = e - e1;
  return __uint_as_float((unsigned)(e1 + 127) << 23) *
         __uint_as_float((unsigned)(e2 + 127) << 23);
}

// quantize y (already divided by shared scale) to e2m<MFRAC>, round-half-even, saturate
template <int MFRAC>
__device__ __forceinline__ float qelem(float y, float maxn) {
  float ay = fabsf(y);
  int e = (ay == 0.f) ? 0 : flog2(ay);
  if (e < 0) e = 0;  // min_exp = 0 for ebits=2
  float r = rintf(y * exp2i(MFRAC - e)) * exp2i(e - MFRAC);
  return fminf(fmaxf(r, -maxn), maxn);
}

// general RNE fp32 -> OCP e4m3 encode (|v| <= 448; exact on our folded value grid)
__device__ __forceinline__ unsigned char enc_rne(float v) {
  unsigned u = __float_as_uint(v);
  unsigned s = u >> 31;
  float a = fabsf(v);
  if (a == 0.f) return (unsigned char)(s << 7);
  int e = flog2(a);
  if (e < -6) e = -6;                      // subnormal regime
  int qi = (int)rintf(a * exp2i(3 - e));   // RNE to 3-frac-bit grid -> [0,16]
  if (qi == 0) return (unsigned char)(s << 7);
  if (qi == 16) { qi = 8; e += 1; }
  unsigned exf, m;
  if (qi < 8) { exf = 0u; m = (unsigned)qi; }          // e == -6 subnormal
  else { exf = (unsigned)(e + 7); m = (unsigned)(qi - 8); }
  return (unsigned char)((s << 7) | (exf << 3) | m);
}

// fragment-page swizzle (CONTIGUOUS-LANE layout): 2KB page per (16-row x 128-K block);
// lane l = (row&15) + ((k>>5)&3)*16 holds k-bytes [ (l>>4)*32 , +32 ) CONTIGUOUSLY at
// page + l*32. pa = K/128 pages per row-block.
__device__ __forceinline__ size_t swz(int row, int col, int pa) {
  return ((size_t)((row >> 4) * pa + (col >> 7))) * 2048
       + (size_t)((((row & 15) + (((col >> 5) & 3) << 4)) << 5) + (col & 31));
}

// ------ MX quantization with exponent folding -> fragment-page-swizzled e4m3 bytes ---
template <int MFRAC, int EMAX>
__global__ void quant_fold(const float* __restrict__ in, unsigned char* __restrict__ out,
                           long n4, float maxn, int se0, int kshift, int kmask, int pa) {
  long i = (long)blockIdx.x * blockDim.x + threadIdx.x;
  long stride = (long)gridDim.x * blockDim.x;
  for (; i < n4; i += stride) {
    float4 v = reinterpret_cast<const float4*>(in)[i];
    float am = fmaxf(fmaxf(fabsf(v.x), fabsf(v.y)), fmaxf(fabsf(v.z), fabsf(v.w)));
    am = fmaxf(am, __shfl_xor(am, 1));
    am = fmaxf(am, __shfl_xor(am, 2));
    am = fmaxf(am, __shfl_xor(am, 4));
    int se = ((am == 0.f) ? 0 : flog2(am)) - EMAX;
    se = se < -127 ? -127 : (se > 127 ? 127 : se);
    float inv = exp2i(-se), f = exp2i(se - se0);
    unsigned o = (unsigned)enc_rne(qelem<MFRAC>(v.x * inv, maxn) * f)
               | ((unsigned)enc_rne(qelem<MFRAC>(v.y * inv, maxn) * f) << 8)
               | ((unsigned)enc_rne(qelem<MFRAC>(v.z * inv, maxn) * f) << 16)
               | ((unsigned)enc_rne(qelem<MFRAC>(v.w * inv, maxn) * f) << 24);
    int row = (int)(i >> kshift);
    int kq = ((int)i & kmask) * 4;           // 4B stays inside the lane's 32B chunk
    reinterpret_cast<unsigned*>(out)[swz(row, kq, pa) >> 2] = o;
  }
}

// load one MFMA fragment: lane's 32B is CONTIGUOUS -> single i32x8 load
// (lowered to 2x global_load_dwordx4 into one adjacent 8-reg tuple, no v_movs)
__device__ __forceinline__ i32x8 gfrag(const unsigned char* page, int l32) {
  return *reinterpret_cast<const i32x8*>(page + l32);
}

// ----- FUSED gate+up GEMM, 16x16x128 MFMA, NO LDS / NO BARRIERS -------------------
// Block 128x128 (S x I), 4 waves (2x2 of 64x64 output, DUAL accumulators).
// Per K-step: 12 gfrag (4 A shared + 4 Bg + 4 Bu) feed 32 MFMAs (16 gate + 16 up).
// silu(g)*u + fp6-MX requant in-register -> iq8 pages; gate never touches memory.
__global__ __launch_bounds__(256, 2) void mx_gateup(
    const unsigned char* __restrict__ A, int pa,
    const unsigned char* __restrict__ Bg, const unsigned char* __restrict__ Bu, int pb,
    unsigned char* __restrict__ C8, int ldC, float fac, int se0out, int nby) {
  const int t = threadIdx.x, l = t & 63, w = t >> 6;
  const int wr = w >> 1, wc = w & 1;          // 2x2 wave grid; wave output 64x64
  const int lr16 = l & 15, lg16 = l >> 4;
  const int l32 = l * 32;
  const int n = (int)blockIdx.x;
  const int bx = n % 32, by = n / 32;          // 32 x nby grid
  const int rowA = bx * 128, rowB = by * 128;
  const int SCL = 0x7f7f7f7f;  // e8m0 1.0 in every byte: scale path is a no-op

  f32x4 accg[4][4], accu[4][4];
#pragma unroll
  for (int i = 0; i < 4; ++i)
#pragma unroll
    for (int j = 0; j < 4; ++j) { accg[i][j] = (f32x4)(0.f); accu[i][j] = (f32x4)(0.f); }

  const unsigned char* pApg[4];
  const unsigned char* pBg[4];
  const unsigned char* pBu[4];
#pragma unroll
  for (int m = 0; m < 4; ++m) {
    pApg[m] = A + (size_t)((rowA >> 4) + wr * 4 + m) * pa * 2048;
    pBg[m] = Bg + (size_t)((rowB >> 4) + wc * 4 + m) * pb * 2048;
    pBu[m] = Bu + (size_t)((rowB >> 4) + wc * 4 + m) * pb * 2048;
  }

  const int nt = pa;  // K = 2048 -> 16 pages
#pragma unroll 2
  for (int kb = 0; kb < nt; ++kb) {
    i32x8 af[4], bg[4], bu[4];
#pragma unroll
    for (int m = 0; m < 4; ++m) { af[m] = gfrag(pApg[m], l32); pApg[m] += 2048; }
#pragma unroll
    for (int m = 0; m < 4; ++m) { bg[m] = gfrag(pBg[m], l32); pBg[m] += 2048; }
#pragma unroll
    for (int m = 0; m < 4; ++m) { bu[m] = gfrag(pBu[m], l32); pBu[m] += 2048; }
#pragma unroll
    for (int m = 0; m < 4; ++m)
#pragma unroll
      for (int nn = 0; nn < 4; ++nn) {
        accg[m][nn] = __builtin_amdgcn_mfma_scale_f32_16x16x128_f8f6f4(
            af[m], bg[nn], accg[m][nn], 0, 0, 0, SCL, 0, SCL);
        accu[m][nn] = __builtin_amdgcn_mfma_scale_f32_16x16x128_f8f6f4(
            af[m], bu[nn], accu[m][nn], 0, 0, 0, SCL, 0, SCL);
      }
  }

  // epilogue: v = silu(g)*u, fp6-MX requant along 32-col blocks, fp8 out (pages)
  // 16x16 C/D layout: col = lane&15, row = (lane>>4)*4 + reg  (m89-verified)
  const int pao = ldC >> 7;
#pragma unroll
  for (int m = 0; m < 4; ++m)
#pragma unroll
    for (int p = 0; p < 2; ++p)
#pragma unroll
      for (int r = 0; r < 4; ++r) {
        int row = rowA + wr * 64 + m * 16 + lg16 * 4 + r;
        int col = rowB + wc * 64 + p * 32 + lr16;
        float g0 = accg[m][2 * p][r] * fac;
        float g1 = accg[m][2 * p + 1][r] * fac;
        float u0 = accu[m][2 * p][r] * fac;
        float u1 = accu[m][2 * p + 1][r] * fac;
        float v0 = u0 * (g0 / (1.f + expf(-g0)));
        float v1 = u1 * (g1 / (1.f + expf(-g1)));
        float am = fmaxf(fabsf(v0), fabsf(v1));
        am = fmaxf(am, __shfl_xor(am, 1));
        am = fmaxf(am, __shfl_xor(am, 2));
        am = fmaxf(am, __shfl_xor(am, 4));
        am = fmaxf(am, __shfl_xor(am, 8));
        int se = ((am == 0.f) ? 0 : flog2(am)) - 2;
        se = se < -127 ? -127 : (se > 127 ? 127 : se);
        float f = exp2i(-se), fo = exp2i(se - se0out);
        C8[swz(row, col, pao)] = enc_rne(qelem<3>(v0 * f, 7.5f) * fo);
        C8[swz(row, col + 16, pao)] = enc_rne(qelem<3>(v1 * f, 7.5f) * fo);
      }
}

// ----- down GEMM (R17 structure): wave tile 64x128, fp32 out, K-split via Cf/Cf2 ----
__global__ __launch_bounds__(256, 2) void mx_down(
    const unsigned char* __restrict__ A, int pa,
    const unsigned char* __restrict__ B, int pb,
    float* __restrict__ Cf, float* __restrict__ Cf2,
    int K, int ldC, float fac, int nby) {
  const int t = threadIdx.x, l = t & 63, w = t >> 6;
  const int wr = w >> 1, wc = w & 1;          // 2x2 wave grid; wave tile 64x128
  const int lr16 = l & 15, lg16 = l >> 4;
  const int l32 = l * 32;
  const int n = (int)blockIdx.x;
  const int bx = n & 31, byks = n >> 5;
  const int by = byks % nby, ks = byks / nby;
  const int rowA = bx * 128, rowB = by * 256;
  const int kbs = ks * (K >> 7);
  const int SCL = 0x7f7f7f7f;

  f32x4 acc[4][8];
#pragma unroll
  for (int i = 0; i < 4; ++i)
#pragma unroll
    for (int j = 0; j < 8; ++j) acc[i][j] = (f32x4)(0.f);

  const unsigned char* pApg[4];
  const unsigned char* pBpg[8];
#pragma unroll
  for (int m = 0; m < 4; ++m)
    pApg[m] = A + ((size_t)((rowA >> 4) + wr * 4 + m) * pa + kbs) * 2048;
#pragma unroll
  for (int nn = 0; nn < 8; ++nn)
    pBpg[nn] = B + ((size_t)((rowB >> 4) + wc * 8 + nn) * pb + kbs) * 2048;

  const int nt = K >> 7;
#pragma unroll 2
  for (int kb = 0; kb < nt; ++kb) {
    i32x8 af[4], bf[8];
#pragma unroll
    for (int m = 0; m < 4; ++m) { af[m] = gfrag(pApg[m], l32); pApg[m] += 2048; }
#pragma unroll
    for (int nn = 0; nn < 8; ++nn) { bf[nn] = gfrag(pBpg[nn], l32); pBpg[nn] += 2048; }
#pragma unroll
    for (int m = 0; m < 4; ++m)
#pragma unroll
      for (int nn = 0; nn < 8; ++nn)
        acc[m][nn] = __builtin_amdgcn_mfma_scale_f32_16x16x128_f8f6f4(
            af[m], bf[nn], acc[m][nn], 0, 0, 0, SCL, 0, SCL);
  }

  float* D = ks ? Cf2 : Cf;
#pragma unroll
  for (int m = 0; m < 4; ++m)
#pragma unroll
    for (int nn = 0; nn < 8; ++nn)
#pragma unroll
      for (int r = 0; r < 4; ++r) {
        int row = rowA + wr * 64 + m * 16 + lg16 * 4 + r;
        int col = rowB + wc * 128 + nn * 16 + lr16;
        D[(size_t)row * ldC + col] = acc[m][nn][r] * fac;
      }
}

__global__ void add_f32(float* __restrict__ out, const float* __restrict__ part, long n4) {
  long i = (long)blockIdx.x * blockDim.x + threadIdx.x;
  long stride = (long)gridDim.x * blockDim.x;
  for (; i < n4; i += stride) {
    float4 a = reinterpret_cast<float4*>(out)[i];
    float4 b = reinterpret_cast<const float4*>(part)[i];
    a.x += b.x; a.y += b.y; a.z += b.z; a.w += b.w;
    reinterpret_cast<float4*>(out)[i] = a;
  }
}

extern "C" void kernel_launch(void* const* d_in, const int* in_sizes, int n_in,
                              void* d_out, int out_size, void* d_ws, size_t ws_size,
                              hipStream_t stream) {
  const float* x = (const float*)d_in[0];
  const float* wg = (const float*)d_in[1];
  const float* wu = (const float*)d_in[2];
  const float* wd = (const float*)d_in[3];
  float* out = (float*)d_out;

  const int S = 4096, H = 2048, I = 8192;

  // per-tensor fold baselines: exact while block se in [se0-6, se0+5]
  const int SE0X = -1, SE0W = -7, SE0I = -2;
  const float FAC_GU = 0.00390625f;     // 2^(SE0X + SE0W) = 2^-8
  const float FAC_DN = 0.001953125f;    // 2^(SE0I + SE0W) = 2^-9

  unsigned char* p = (unsigned char*)d_ws;
  unsigned char* xq8 = p;  p += (size_t)S * H;   //  8.4 MB (swizzled pages)
  unsigned char* wgq8 = p; p += (size_t)I * H;   // 16.8 MB
  unsigned char* wuq8 = p; p += (size_t)I * H;   // 16.8 MB
  unsigned char* wdq8 = p; p += (size_t)H * I;   // 16.8 MB
  unsigned char* iq8 = p;  p += (size_t)S * I;   // 33.6 MB
  float* pf = (float*)p;                         // down K-split partial, 33.6 MB

  // quantize -> fragment-page-swizzled e4m3
  quant_fold<3, 2><<<2048, 256, 0, stream>>>(x, xq8, (long)S * H / 4, 7.5f, SE0X,
                                             9, 511, H / 128);    // K=2048
  quant_fold<1, 2><<<2048, 256, 0, stream>>>(wg, wgq8, (long)I * H / 4, 6.0f, SE0W,
                                             9, 511, H / 128);
  quant_fold<1, 2><<<2048, 256, 0, stream>>>(wu, wuq8, (long)I * H / 4, 6.0f, SE0W,
                                             9, 511, H / 128);
  quant_fold<1, 2><<<2048, 256, 0, stream>>>(wd, wdq8, (long)H * I / 4, 6.0f, SE0W,
                                             11, 2047, I / 128);  // K=8192

  // fused gate+up + SwiGLU + fp6-MX requant -> iq8 pages (grid 32 x 64 = 2048)
  mx_gateup<<<32 * (I / 128), 256, 0, stream>>>(
      xq8, H / 128, wgq8, wuq8, H / 128, iq8, I, FAC_GU, SE0I, I / 128);

  // down GEMM, K split in 2 (K = I/2 per half; grid 32*8*2 = 512)
  mx_down<<<32 * (H / 256) * 2, 256, 0, stream>>>(
      iq8, I / 128, wdq8, I / 128, out, pf, I / 2, H, FAC_DN, H / 256);
  add_f32<<<2048, 256, 0, stream>>>(out, pf, (long)S * H / 4);
}

// Round 24
// 415.011 us; speedup vs baseline: 1.8611x; 1.0004x over previous
//
#include <hip/hip_runtime.h>
#include <hip/hip_bf16.h>

typedef __attribute__((ext_vector_type(4))) int i32x4;
typedef __attribute__((ext_vector_type(8))) int i32x8;
typedef __attribute__((ext_vector_type(4))) float f32x4;

// exact floor(log2(x)) for x > 0 (handles subnormals)
__device__ __forceinline__ int flog2(float x) {
  unsigned u = __float_as_uint(x);
  int e = (int)((u >> 23) & 255u);
  if (e) return e - 127;
  unsigned m = u & 0x7fffffu;
  return (31 - __clz(m)) - 149;
}

// exact 2^e for e in [-252, 254]
__device__ __forceinline__ float exp2i(int e) {
  int e1 = e >> 1, e2 = e - e1;
  return __uint_as_float((unsigned)(e1 + 127) << 23) *
         __uint_as_float((unsigned)(e2 + 127) << 23);
}

// quantize y (already divided by shared scale) to e2m<MFRAC>, round-half-even, saturate
template <int MFRAC>
__device__ __forceinline__ float qelem(float y, float maxn) {
  float ay = fabsf(y);
  int e = (ay == 0.f) ? 0 : flog2(ay);
  if (e < 0) e = 0;  // min_exp = 0 for ebits=2
  float r = rintf(y * exp2i(MFRAC - e)) * exp2i(e - MFRAC);
  return fminf(fmaxf(r, -maxn), maxn);
}

// general RNE fp32 -> OCP e4m3 encode (|v| <= 448; exact on our folded value grid)
__device__ __forceinline__ unsigned char enc_rne(float v) {
  unsigned u = __float_as_uint(v);
  unsigned s = u >> 31;
  float a = fabsf(v);
  if (a == 0.f) return (unsigned char)(s << 7);
  int e = flog2(a);
  if (e < -6) e = -6;                      // subnormal regime
  int qi = (int)rintf(a * exp2i(3 - e));   // RNE to 3-frac-bit grid -> [0,16]
  if (qi == 0) return (unsigned char)(s << 7);
  if (qi == 16) { qi = 8; e += 1; }
  unsigned exf, m;
  if (qi < 8) { exf = 0u; m = (unsigned)qi; }          // e == -6 subnormal
  else { exf = (unsigned)(e + 7); m = (unsigned)(qi - 8); }
  return (unsigned char)((s << 7) | (exf << 3) | m);
}

// fragment-page swizzle (CONTIGUOUS-LANE layout): 2KB page per (16-row x 128-K block);
// lane l = (row&15) + ((k>>5)&3)*16 holds k-bytes [ (l>>4)*32 , +32 ) CONTIGUOUSLY at
// page + l*32. pa = K/128 pages per row-block.
__device__ __forceinline__ size_t swz(int row, int col, int pa) {
  return ((size_t)((row >> 4) * pa + (col >> 7))) * 2048
       + (size_t)((((row & 15) + (((col >> 5) & 3) << 4)) << 5) + (col & 31));
}

// ------ MX quantization with exponent folding -> fragment-page-swizzled e4m3 bytes ---
template <int MFRAC, int EMAX>
__global__ void quant_fold(const float* __restrict__ in, unsigned char* __restrict__ out,
                           long n4, float maxn, int se0, int kshift, int kmask, int pa) {
  long i = (long)blockIdx.x * blockDim.x + threadIdx.x;
  long stride = (long)gridDim.x * blockDim.x;
  for (; i < n4; i += stride) {
    float4 v = reinterpret_cast<const float4*>(in)[i];
    float am = fmaxf(fmaxf(fabsf(v.x), fabsf(v.y)), fmaxf(fabsf(v.z), fabsf(v.w)));
    am = fmaxf(am, __shfl_xor(am, 1));
    am = fmaxf(am, __shfl_xor(am, 2));
    am = fmaxf(am, __shfl_xor(am, 4));
    int se = ((am == 0.f) ? 0 : flog2(am)) - EMAX;
    se = se < -127 ? -127 : (se > 127 ? 127 : se);
    float inv = exp2i(-se), f = exp2i(se - se0);
    unsigned o = (unsigned)enc_rne(qelem<MFRAC>(v.x * inv, maxn) * f)
               | ((unsigned)enc_rne(qelem<MFRAC>(v.y * inv, maxn) * f) << 8)
               | ((unsigned)enc_rne(qelem<MFRAC>(v.z * inv, maxn) * f) << 16)
               | ((unsigned)enc_rne(qelem<MFRAC>(v.w * inv, maxn) * f) << 24);
    int row = (int)(i >> kshift);
    int kq = ((int)i & kmask) * 4;           // 4B stays inside the lane's 32B chunk
    reinterpret_cast<unsigned*>(out)[swz(row, kq, pa) >> 2] = o;
  }
}

// load one MFMA fragment: lane's 32B is CONTIGUOUS -> single i32x8 load
__device__ __forceinline__ i32x8 gfrag(const unsigned char* page, int l32) {
  return *reinterpret_cast<const i32x8*>(page + l32);
}

// ----- FUSED gate+up GEMM, 16x16x128 MFMA, NO LDS / NO BARRIERS -------------------
// Block 128x128 (S x I), 4 waves (2x2 of 64x64 output, DUAL accumulators).
// XCD-aware work mapping: HW dispatches block n to XCD n%8; we assign XCD x the
// by-panel range [x*8, x*8+8) so its Bg+Bu panels (8 x 2 x 256KB = 4MB) stay
// L2-resident; bx scans inner (temporal locality on the panel).
__global__ __launch_bounds__(256, 2) void mx_gateup(
    const unsigned char* __restrict__ A, int pa,
    const unsigned char* __restrict__ Bg, const unsigned char* __restrict__ Bu, int pb,
    unsigned char* __restrict__ C8, int ldC, float fac, int se0out) {
  const int t = threadIdx.x, l = t & 63, w = t >> 6;
  const int wr = w >> 1, wc = w & 1;          // 2x2 wave grid; wave output 64x64
  const int lr16 = l & 15, lg16 = l >> 4;
  const int l32 = l * 32;
  const int n = (int)blockIdx.x;               // grid 2048 = 8 xcd * 32 bx * 8 byl
  const int xcd = n & 7, i = n >> 3;
  const int bx = i & 31, byl = i >> 5;         // bx inner in time
  const int by = xcd * 8 + byl;
  const int rowA = bx * 128, rowB = by * 128;
  const int SCL = 0x7f7f7f7f;  // e8m0 1.0 in every byte: scale path is a no-op

  f32x4 accg[4][4], accu[4][4];
#pragma unroll
  for (int i2 = 0; i2 < 4; ++i2)
#pragma unroll
    for (int j = 0; j < 4; ++j) { accg[i2][j] = (f32x4)(0.f); accu[i2][j] = (f32x4)(0.f); }

  const unsigned char* pApg[4];
  const unsigned char* pBg[4];
  const unsigned char* pBu[4];
#pragma unroll
  for (int m = 0; m < 4; ++m) {
    pApg[m] = A + (size_t)((rowA >> 4) + wr * 4 + m) * pa * 2048;
    pBg[m] = Bg + (size_t)((rowB >> 4) + wc * 4 + m) * pb * 2048;
    pBu[m] = Bu + (size_t)((rowB >> 4) + wc * 4 + m) * pb * 2048;
  }

  const int nt = pa;  // K = 2048 -> 16 pages
#pragma unroll 4
  for (int kb = 0; kb < nt; ++kb) {
    i32x8 af[4], bg[4], bu[4];
#pragma unroll
    for (int m = 0; m < 4; ++m) { af[m] = gfrag(pApg[m], l32); pApg[m] += 2048; }
#pragma unroll
    for (int m = 0; m < 4; ++m) { bg[m] = gfrag(pBg[m], l32); pBg[m] += 2048; }
#pragma unroll
    for (int m = 0; m < 4; ++m) { bu[m] = gfrag(pBu[m], l32); pBu[m] += 2048; }
    __builtin_amdgcn_s_setprio(1);
#pragma unroll
    for (int m = 0; m < 4; ++m)
#pragma unroll
      for (int nn = 0; nn < 4; ++nn) {
        accg[m][nn] = __builtin_amdgcn_mfma_scale_f32_16x16x128_f8f6f4(
            af[m], bg[nn], accg[m][nn], 0, 0, 0, SCL, 0, SCL);
        accu[m][nn] = __builtin_amdgcn_mfma_scale_f32_16x16x128_f8f6f4(
            af[m], bu[nn], accu[m][nn], 0, 0, 0, SCL, 0, SCL);
      }
    __builtin_amdgcn_s_setprio(0);
  }

  // epilogue: v = silu(g)*u, fp6-MX requant along 32-col blocks, fp8 out (pages)
  // 16x16 C/D layout: col = lane&15, row = (lane>>4)*4 + reg  (m89-verified)
  const int pao = ldC >> 7;
#pragma unroll
  for (int m = 0; m < 4; ++m)
#pragma unroll
    for (int p = 0; p < 2; ++p)
#pragma unroll
      for (int r = 0; r < 4; ++r) {
        int row = rowA + wr * 64 + m * 16 + lg16 * 4 + r;
        int col = rowB + wc * 64 + p * 32 + lr16;
        float g0 = accg[m][2 * p][r] * fac;
        float g1 = accg[m][2 * p + 1][r] * fac;
        float u0 = accu[m][2 * p][r] * fac;
        float u1 = accu[m][2 * p + 1][r] * fac;
        float v0 = u0 * (g0 / (1.f + expf(-g0)));
        float v1 = u1 * (g1 / (1.f + expf(-g1)));
        float am = fmaxf(fabsf(v0), fabsf(v1));
        am = fmaxf(am, __shfl_xor(am, 1));
        am = fmaxf(am, __shfl_xor(am, 2));
        am = fmaxf(am, __shfl_xor(am, 4));
        am = fmaxf(am, __shfl_xor(am, 8));
        int se = ((am == 0.f) ? 0 : flog2(am)) - 2;
        se = se < -127 ? -127 : (se > 127 ? 127 : se);
        float f = exp2i(-se), fo = exp2i(se - se0out);
        C8[swz(row, col, pao)] = enc_rne(qelem<3>(v0 * f, 7.5f) * fo);
        C8[swz(row, col + 16, pao)] = enc_rne(qelem<3>(v1 * f, 7.5f) * fo);
      }
}

// ----- down GEMM: wave tile 64x128, fp32 out, K-split via Cf/Cf2, XCD-mapped --------
// grid 512 = 8 xcd * 32 bx * 2 slot; XCD x owns 2 (by,ks) slots -> wd panel 2x1MB L2-hot.
__global__ __launch_bounds__(256, 2) void mx_down(
    const unsigned char* __restrict__ A, int pa,
    const unsigned char* __restrict__ B, int pb,
    float* __restrict__ Cf, float* __restrict__ Cf2,
    int K, int ldC, float fac) {
  const int t = threadIdx.x, l = t & 63, w = t >> 6;
  const int wr = w >> 1, wc = w & 1;          // 2x2 wave grid; wave tile 64x128
  const int lr16 = l & 15, lg16 = l >> 4;
  const int l32 = l * 32;
  const int n = (int)blockIdx.x;
  const int xcd = n & 7, i = n >> 3;
  const int bx = i & 31, slot = i >> 5;        // slot in [0,2)
  const int byks = xcd * 2 + slot;             // 16 slots = 8 by * 2 ks
  const int by = byks & 7, ks = byks >> 3;
  const int rowA = bx * 128, rowB = by * 256;
  const int kbs = ks * (K >> 7);
  const int SCL = 0x7f7f7f7f;

  f32x4 acc[4][8];
#pragma unroll
  for (int i2 = 0; i2 < 4; ++i2)
#pragma unroll
    for (int j = 0; j < 8; ++j) acc[i2][j] = (f32x4)(0.f);

  const unsigned char* pApg[4];
  const unsigned char* pBpg[8];
#pragma unroll
  for (int m = 0; m < 4; ++m)
    pApg[m] = A + ((size_t)((rowA >> 4) + wr * 4 + m) * pa + kbs) * 2048;
#pragma unroll
  for (int nn = 0; nn < 8; ++nn)
    pBpg[nn] = B + ((size_t)((rowB >> 4) + wc * 8 + nn) * pb + kbs) * 2048;

  const int nt = K >> 7;
#pragma unroll 4
  for (int kb = 0; kb < nt; ++kb) {
    i32x8 af[4], bf[8];
#pragma unroll
    for (int m = 0; m < 4; ++m) { af[m] = gfrag(pApg[m], l32); pApg[m] += 2048; }
#pragma unroll
    for (int nn = 0; nn < 8; ++nn) { bf[nn] = gfrag(pBpg[nn], l32); pBpg[nn] += 2048; }
    __builtin_amdgcn_s_setprio(1);
#pragma unroll
    for (int m = 0; m < 4; ++m)
#pragma unroll
      for (int nn = 0; nn < 8; ++nn)
        acc[m][nn] = __builtin_amdgcn_mfma_scale_f32_16x16x128_f8f6f4(
            af[m], bf[nn], acc[m][nn], 0, 0, 0, SCL, 0, SCL);
    __builtin_amdgcn_s_setprio(0);
  }

  float* D = ks ? Cf2 : Cf;
#pragma unroll
  for (int m = 0; m < 4; ++m)
#pragma unroll
    for (int nn = 0; nn < 8; ++nn)
#pragma unroll
      for (int r = 0; r < 4; ++r) {
        int row = rowA + wr * 64 + m * 16 + lg16 * 4 + r;
        int col = rowB + wc * 128 + nn * 16 + lr16;
        D[(size_t)row * ldC + col] = acc[m][nn][r] * fac;
      }
}

__global__ void add_f32(float* __restrict__ out, const float* __restrict__ part, long n4) {
  long i = (long)blockIdx.x * blockDim.x + threadIdx.x;
  long stride = (long)gridDim.x * blockDim.x;
  for (; i < n4; i += stride) {
    float4 a = reinterpret_cast<float4*>(out)[i];
    float4 b = reinterpret_cast<const float4*>(part)[i];
    a.x += b.x; a.y += b.y; a.z += b.z; a.w += b.w;
    reinterpret_cast<float4*>(out)[i] = a;
  }
}

extern "C" void kernel_launch(void* const* d_in, const int* in_sizes, int n_in,
                              void* d_out, int out_size, void* d_ws, size_t ws_size,
                              hipStream_t stream) {
  const float* x = (const float*)d_in[0];
  const float* wg = (const float*)d_in[1];
  const float* wu = (const float*)d_in[2];
  const float* wd = (const float*)d_in[3];
  float* out = (float*)d_out;

  const int S = 4096, H = 2048, I = 8192;

  // per-tensor fold baselines: exact while block se in [se0-6, se0+5]
  const int SE0X = -1, SE0W = -7, SE0I = -2;
  const float FAC_GU = 0.00390625f;     // 2^(SE0X + SE0W) = 2^-8
  const float FAC_DN = 0.001953125f;    // 2^(SE0I + SE0W) = 2^-9

  unsigned char* p = (unsigned char*)d_ws;
  unsigned char* xq8 = p;  p += (size_t)S * H;   //  8.4 MB (swizzled pages)
  unsigned char* wgq8 = p; p += (size_t)I * H;   // 16.8 MB
  unsigned char* wuq8 = p; p += (size_t)I * H;   // 16.8 MB
  unsigned char* wdq8 = p; p += (size_t)H * I;   // 16.8 MB
  unsigned char* iq8 = p;  p += (size_t)S * I;   // 33.6 MB
  float* pf = (float*)p;                         // down K-split partial, 33.6 MB

  // quantize -> fragment-page-swizzled e4m3
  quant_fold<3, 2><<<2048, 256, 0, stream>>>(x, xq8, (long)S * H / 4, 7.5f, SE0X,
                                             9, 511, H / 128);    // K=2048
  quant_fold<1, 2><<<2048, 256, 0, stream>>>(wg, wgq8, (long)I * H / 4, 6.0f, SE0W,
                                             9, 511, H / 128);
  quant_fold<1, 2><<<2048, 256, 0, stream>>>(wu, wuq8, (long)I * H / 4, 6.0f, SE0W,
                                             9, 511, H / 128);
  quant_fold<1, 2><<<2048, 256, 0, stream>>>(wd, wdq8, (long)H * I / 4, 6.0f, SE0W,
                                             11, 2047, I / 128);  // K=8192

  // fused gate+up + SwiGLU + fp6-MX requant -> iq8 pages (grid 2048, XCD-mapped)
  mx_gateup<<<32 * (I / 128), 256, 0, stream>>>(
      xq8, H / 128, wgq8, wuq8, H / 128, iq8, I, FAC_GU, SE0I);

  // down GEMM, K split in 2 (K = I/2 per half; grid 512, XCD-mapped)
  mx_down<<<512, 256, 0, stream>>>(
      iq8, I / 128, wdq8, I / 128, out, pf, I / 2, H, FAC_DN);
  add_f32<<<2048, 256, 0, stream>>>(out, pf, (long)S * H / 4);
}